// Round 1
// baseline (165.274 us; speedup 1.0000x reference)
//
#include <hip/hip_runtime.h>
#include <math.h>

#define N_PTS 16384
#define EPS 1e-7f

// Persistent device scratch (fully rewritten every launch; no cross-call state relied on).
__device__ float4 g_est[N_PTS];
__device__ float4 g_gt[N_PTS];
__device__ float  g_chamfer;
__device__ float  g_l2;
__device__ int    g_cnt;

__global__ void init_acc_kernel() {
    g_chamfer = 0.0f;
    g_l2 = 0.0f;
    g_cnt = 0;
}

__global__ void transform_kernel(const float* __restrict__ pts,
                                 const int* __restrict__ ti,
                                 const float* __restrict__ est_poses,
                                 const float* __restrict__ gt_poses) {
    int n = blockIdx.x * blockDim.x + threadIdx.x;
    float l2v = 0.0f;
    int cnt = 0;
    if (n < N_PTS) {
        float px = pts[3 * n + 0];
        float py = pts[3 * n + 1];
        float pz = pts[3 * n + 2];
        int t = ti[n];
        const float* PE = est_poses + t * 16;
        const float* PG = gt_poses + t * 16;
        float ex = PE[0] * px + PE[1] * py + PE[2]  * pz + PE[3];
        float ey = PE[4] * px + PE[5] * py + PE[6]  * pz + PE[7];
        float ez = PE[8] * px + PE[9] * py + PE[10] * pz + PE[11];
        float gx = PG[0] * px + PG[1] * py + PG[2]  * pz + PG[3];
        float gy = PG[4] * px + PG[5] * py + PG[6]  * pz + PG[7];
        float gz = PG[8] * px + PG[9] * py + PG[10] * pz + PG[11];
        g_est[n] = make_float4(ex, ey, ez, ex * ex + ey * ey + ez * ez);
        g_gt[n]  = make_float4(gx, gy, gz, gx * gx + gy * gy + gz * gz);
        if (t == 1) {
            cnt = 1;
            float dx = ex - gx, dy = ey - gy, dz = ez - gz;
            l2v = sqrtf(dx * dx + dy * dy + dz * dz);
        }
    }
    // wave-64 reduction, then one atomic per wave
    #pragma unroll
    for (int o = 32; o > 0; o >>= 1) {
        l2v += __shfl_down(l2v, o);
        cnt += __shfl_down(cnt, o);
    }
    if ((threadIdx.x & 63) == 0) {
        if (l2v != 0.0f) atomicAdd(&g_l2, l2v);
        if (cnt) atomicAdd(&g_cnt, cnt);
    }
}

// One wave per (side, point). side 0: dist1[i] = min_j d2(gt_i, est_j)
//                             side 1: dist2[j] = min_i d2(est_j, gt_i)
__global__ void chamfer_kernel(const int* __restrict__ ti) {
    int wave = (blockIdx.x * blockDim.x + threadIdx.x) >> 6;
    int lane = threadIdx.x & 63;
    int side = wave >> 14;           // 16384 waves per side
    int i = wave & (N_PTS - 1);
    if (ti[i] != 1) return;          // w[i]==0 -> contributes nothing

    const float4* __restrict__ P = side ? g_est : g_gt;
    const float4* __restrict__ Q = side ? g_gt : g_est;
    float4 p = P[i];

    float m = 3.4e38f;
    for (int j = lane; j < N_PTS; j += 64) {
        float4 q = Q[j];
        // identical formula to reference: |p|^2 + |q|^2 - 2 p.q
        float d = p.w + q.w - 2.0f * (p.x * q.x + p.y * q.y + p.z * q.z);
        m = fminf(m, d);
    }
    #pragma unroll
    for (int o = 32; o > 0; o >>= 1) {
        m = fminf(m, __shfl_xor(m, o));
    }
    if (lane == 0) atomicAdd(&g_chamfer, m);
}

__global__ void finalize_kernel(float* __restrict__ out) {
    float inv = 1.0f / ((float)g_cnt + EPS);
    out[0] = 0.5f * g_chamfer * inv;
    out[1] = g_l2 * inv;
}

extern "C" void kernel_launch(void* const* d_in, const int* in_sizes, int n_in,
                              void* d_out, int out_size, void* d_ws, size_t ws_size,
                              hipStream_t stream) {
    const float* pts       = (const float*)d_in[0];
    const int*   ti        = (const int*)d_in[1];
    const float* est_poses = (const float*)d_in[2];
    const float* gt_poses  = (const float*)d_in[3];
    float* out = (float*)d_out;

    init_acc_kernel<<<1, 1, 0, stream>>>();
    transform_kernel<<<N_PTS / 256, 256, 0, stream>>>(pts, ti, est_poses, gt_poses);
    // 2 * 16384 waves, 4 waves per 256-thread block -> 8192 blocks
    chamfer_kernel<<<(2 * N_PTS) / 4, 256, 0, stream>>>(ti);
    finalize_kernel<<<1, 1, 0, stream>>>(out);
}

// Round 2
// 39.144 us; speedup vs baseline: 4.2222x; 4.2222x over previous
//
#include <hip/hip_runtime.h>
#include <math.h>

#define N_PTS  16384
#define EPS    1e-7f
#define PPW    8                 // active points per work-item
#define JSPLIT 8                 // slices of the j-range per point-group
#define JSLICE (N_PTS / JSPLIT)  // 2048

// Persistent device scratch — every element read is written earlier in the
// same launch; no cross-call state is relied on.
__device__ float4 g_est[N_PTS];
__device__ float4 g_gt[N_PTS];
__device__ int    g_active[N_PTS];
__device__ float  g_partial[2 * N_PTS * JSPLIT];

// ws layout (zeroed via hipMemsetAsync each launch):
//   ws32[0] = l2_acc (float), ws32[1] = n_active (int), ws32[2] = chamfer_acc (float)

__global__ void transform_kernel(const float* __restrict__ pts,
                                 const int* __restrict__ ti,
                                 const float* __restrict__ est_poses,
                                 const float* __restrict__ gt_poses,
                                 float* __restrict__ ws) {
    int n = blockIdx.x * blockDim.x + threadIdx.x;   // grid exactly covers N_PTS
    int lane = threadIdx.x & 63;

    float px = pts[3 * n + 0];
    float py = pts[3 * n + 1];
    float pz = pts[3 * n + 2];
    int t = ti[n];
    const float* PE = est_poses + t * 16;
    const float* PG = gt_poses + t * 16;
    float ex = PE[0] * px + PE[1] * py + PE[2]  * pz + PE[3];
    float ey = PE[4] * px + PE[5] * py + PE[6]  * pz + PE[7];
    float ez = PE[8] * px + PE[9] * py + PE[10] * pz + PE[11];
    float gx = PG[0] * px + PG[1] * py + PG[2]  * pz + PG[3];
    float gy = PG[4] * px + PG[5] * py + PG[6]  * pz + PG[7];
    float gz = PG[8] * px + PG[9] * py + PG[10] * pz + PG[11];
    g_est[n] = make_float4(ex, ey, ez, ex * ex + ey * ey + ez * ez);
    g_gt[n]  = make_float4(gx, gy, gz, gx * gx + gy * gy + gz * gz);

    bool active = (t == 1);
    // wave-level compaction: one atomic per wave
    unsigned long long mask = __ballot(active);
    int wcnt = __popcll(mask);
    int base = 0;
    if (lane == 0 && wcnt) base = atomicAdd((int*)ws + 1, wcnt);
    base = __shfl(base, 0);
    if (active) {
        int rank = __popcll(mask & ((1ull << lane) - 1ull));
        g_active[base + rank] = n;
    }

    float dx = ex - gx, dy = ey - gy, dz = ez - gz;
    float l2v = active ? sqrtf(dx * dx + dy * dy + dz * dz) : 0.0f;
    #pragma unroll
    for (int o = 32; o > 0; o >>= 1) l2v += __shfl_down(l2v, o);
    if (lane == 0 && l2v != 0.0f) atomicAdd(ws, l2v);
}

// Work-item = (side, point-group of PPW active points, j-slice of JSLICE).
// Each wave: load PPW p-points into registers, stream its j-slice once,
// keep PPW running mins, store partial mins.
__global__ void chamfer_kernel(const float* __restrict__ ws) {
    int nact = ((const int*)ws)[1];
    if (nact == 0) return;
    int ngroups = (nact + PPW - 1) / PPW;
    int nitems  = 2 * ngroups * JSPLIT;

    int lane   = threadIdx.x & 63;
    int wid    = (blockIdx.x * blockDim.x + threadIdx.x) >> 6;
    int nwaves = (gridDim.x * blockDim.x) >> 6;

    for (int item = wid; item < nitems; item += nwaves) {
        int s    = item % JSPLIT;
        int gidx = item / JSPLIT;
        int side = gidx >= ngroups;
        int g    = side ? gidx - ngroups : gidx;
        int base = g * PPW;
        int cnt_k = min(PPW, nact - base);

        const float4* __restrict__ P = side ? g_est : g_gt;
        const float4* __restrict__ Q = side ? g_gt : g_est;

        float4 p[PPW];
        #pragma unroll
        for (int k = 0; k < PPW; ++k) {
            int kk = k < cnt_k ? k : cnt_k - 1;
            p[k] = P[g_active[base + kk]];
        }

        float m[PPW];
        #pragma unroll
        for (int k = 0; k < PPW; ++k) m[k] = 3.4e38f;

        int j0 = s * JSLICE;
        #pragma unroll 4
        for (int j = j0 + lane; j < j0 + JSLICE; j += 64) {
            float4 q = Q[j];
            #pragma unroll
            for (int k = 0; k < PPW; ++k) {
                // same formula as reference: |p|^2 + |q|^2 - 2 p.q
                float d = p[k].w + q.w -
                          2.0f * (p[k].x * q.x + p[k].y * q.y + p[k].z * q.z);
                m[k] = fminf(m[k], d);
            }
        }

        #pragma unroll
        for (int k = 0; k < PPW; ++k) {
            #pragma unroll
            for (int o = 32; o > 0; o >>= 1)
                m[k] = fminf(m[k], __shfl_xor(m[k], o));
        }
        if (lane == 0) {
            #pragma unroll
            for (int k = 0; k < PPW; ++k)
                if (k < cnt_k)
                    g_partial[(side * N_PTS + base + k) * JSPLIT + s] = m[k];
        }
    }
}

// Min over the JSPLIT partial slices per active point, then weighted sum.
__global__ void combine_kernel(float* __restrict__ ws) {
    int nact  = ((const int*)ws)[1];
    int total = 2 * nact;
    int tid  = blockIdx.x * blockDim.x + threadIdx.x;
    int nthr = gridDim.x * blockDim.x;

    float sum = 0.0f;
    for (int a = tid; a < total; a += nthr) {
        int side = a >= nact;
        int ai   = side ? a - nact : a;
        const float* pp = &g_partial[(side * N_PTS + ai) * JSPLIT];
        float mn = pp[0];
        #pragma unroll
        for (int s = 1; s < JSPLIT; ++s) mn = fminf(mn, pp[s]);
        sum += mn;
    }
    #pragma unroll
    for (int o = 32; o > 0; o >>= 1) sum += __shfl_down(sum, o);
    if ((threadIdx.x & 63) == 0 && sum != 0.0f) atomicAdd(ws + 2, sum);
}

__global__ void finalize_kernel(const float* __restrict__ ws,
                                float* __restrict__ out) {
    float cnt = (float)((const int*)ws)[1];
    float inv = 1.0f / (cnt + EPS);
    out[0] = 0.5f * ws[2] * inv;
    out[1] = ws[0] * inv;
}

extern "C" void kernel_launch(void* const* d_in, const int* in_sizes, int n_in,
                              void* d_out, int out_size, void* d_ws, size_t ws_size,
                              hipStream_t stream) {
    const float* pts       = (const float*)d_in[0];
    const int*   ti        = (const int*)d_in[1];
    const float* est_poses = (const float*)d_in[2];
    const float* gt_poses  = (const float*)d_in[3];
    float* ws  = (float*)d_ws;
    float* out = (float*)d_out;

    hipMemsetAsync(d_ws, 0, 16, stream);
    transform_kernel<<<N_PTS / 256, 256, 0, stream>>>(pts, ti, est_poses, gt_poses, ws);
    // 1024 blocks x 4 waves = 4096 waves; ~3280 items in the common case
    chamfer_kernel<<<1024, 256, 0, stream>>>(ws);
    combine_kernel<<<128, 256, 0, stream>>>(ws);
    finalize_kernel<<<1, 1, 0, stream>>>(ws, out);
}